// Round 14
// baseline (99.472 us; speedup 1.0000x reference)
//
#include <hip/hip_runtime.h>
#include <hip/hip_bf16.h>
#include <stdint.h>

#define NROWS 8192
#define NDIM  512
#define MARGIN 0.3f
#define NT    2080     // 64*65/2 upper-triangular 128x128 blocks

typedef __attribute__((ext_vector_type(16))) float floatx16;
typedef __attribute__((ext_vector_type(8)))  int   intx8;

// pack 4 floats -> 4 OCP e4m3 bytes (HW cvt, RNE, saturating)
__device__ inline unsigned cvt4_fp8(float4 f) {
  int v = 0;
  v = __builtin_amdgcn_cvt_pk_fp8_f32(f.x, f.y, v, false);
  v = __builtin_amdgcn_cvt_pk_fp8_f32(f.z, f.w, v, true);
  return (unsigned)v;
}

// fp32 -> fp8 e4m3, fully coalesced: lane i reads float4 i, writes u32 i
__global__ void convert_kernel(const float4* __restrict__ in, unsigned* __restrict__ out) {
  int i = blockIdx.x * blockDim.x + threadIdx.x;
  out[i] = cvt4_fp8(in[i]);
}

__device__ inline void gload_lds16(const void* g, void* l) {
  __builtin_amdgcn_global_load_lds(
      (const __attribute__((address_space(1))) unsigned int*)g,
      (__attribute__((address_space(3))) unsigned int*)l, 16, 0, 0);
}

// R29 = RESUBMIT of R28 (R13 bench was an infra failure: container died
// before compile/run; no kernel signal). R28 = R7 champion (94.7/95.2us
// reproduced) with ONE single-axis change: prefetch distance 2 -> 3
// (4-stage LDS ring, 64 KB, still exactly 2 blocks/CU). Phases remain
// barrier-per-step (sound, unlike R10: the phase-kt barrier seals reads of
// buffer (kt-1)&3 BEFORE STAGE(kt+3) overwrites it). Waits: kt<6 vmcnt(4)
// [own stage landed, 2 stages in flight], kt==6 vmcnt(2), kt==7 vmcnt(0) —
// never a mid-loop drain. Mechanism target: each phase is an 8-wave convoy
// whose critical path is the TAIL wave's DMA; distance-3 gives that DMA ~3
// compute phases of cover instead of ~2 at zero extra barrier/register
// cost. Everything else byte-identical to R7: 128^2 tile, 8 waves x 64x32,
// 2 DMA loads/wave/stage, R14-verified swizzle, R0-verified epilogue,
// partial store + separate reduce kernel (R11 lesson: no tail edits).
__launch_bounds__(512, 4)
__global__ void loss_kernel(const unsigned char* __restrict__ Xb, const int* __restrict__ tg,
                            float* __restrict__ partials) {
  __shared__ __align__(16) unsigned char As[4][8192];   // 128 rows x 64 B
  __shared__ __align__(16) unsigned char Bs[4][8192];
  __shared__ float red[8];

  // super-tile decode (8 diagonal supers of 36, then 28 off-diag of 64) —
  // exact R0 decode.
  int t = blockIdx.x;
  int bi, bj;
  if (t < 288) {
    int si = t / 36;
    int q  = t - si * 36;
    int ii = 0;
    while (q >= 8 - ii) { q -= 8 - ii; ii++; }
    bi = si * 8 + ii;
    bj = si * 8 + ii + q;
  } else {
    int q = t - 288;
    int s = q >> 6, r = q & 63;
    int si = 0;
    while (s >= 7 - si) { s -= 7 - si; si++; }
    int sj = si + 1 + s;
    bi = si * 8 + (r >> 3);
    bj = sj * 8 + (r & 7);
  }

  const int tid  = threadIdx.x;
  const int lane = tid & 63;
  const int w    = tid >> 6;             // 0..7
  const int wm   = w >> 2, wn = w & 3;   // 2x4 waves, 64x32 each
  const int g    = lane >> 5;            // MFMA k-group (0/1)
  const int m32  = lane & 31;            // MFMA row/col within 32

  const int rowBase = bi * 128;
  const int colBase = bj * 128;

  // staging: tile = 128 rows x 64 B = 8 chunks of 1 KB (16 rows each);
  // wave w stages chunk w of A and chunk w of B (2 DMA loads/wave/stage).
  // Chunk lane d: row = w*16 + (d>>2), u_phys = d&3; fetches global k-unit
  // u_log = u_phys ^ ((row>>2)&3)  (conflict-free b128 reads, R14-verified;
  // (row>>2)&3 == (srow>>2)&3 since w*16 contributes 0 mod 4).
  const int srow = lane >> 2;
  const int sup  = lane & 3;
  const int ul   = sup ^ ((srow >> 2) & 3);
  const int rloc = w * 16 + srow;
  const unsigned gA = (unsigned)((rowBase + rloc) * NDIM + ul * 16);
  const unsigned gB = (unsigned)((colBase + rloc) * NDIM + ul * 16);

#define STAGE(KT, BUF)                                                    \
  do {                                                                    \
    gload_lds16(Xb + gA + (KT) * 64, &As[BUF][w * 1024]);                 \
    gload_lds16(Xb + gB + (KT) * 64, &Bs[BUF][w * 1024]);                 \
  } while (0)

  floatx16 acc[2];
  acc[0] = (floatx16)(0.f);
  acc[1] = (floatx16)(0.f);

  STAGE(0, 0);
  STAGE(1, 1);
  STAGE(2, 2);

#pragma unroll
  for (int kt = 0; kt < 8; kt++) {
    const int buf = kt & 3;
    // own stage kt landed (2 oldest loads retired); up to 2 later stages'
    // loads (4) stay in flight. Tail: kt=6 one stage left, kt=7 none.
    if (kt < 6)      asm volatile("s_waitcnt vmcnt(4)" ::: "memory");
    else if (kt < 7) asm volatile("s_waitcnt vmcnt(2)" ::: "memory");
    else             asm volatile("s_waitcnt vmcnt(0)" ::: "memory");
    asm volatile("s_barrier" ::: "memory");        // raw: no lgkm drain
    if (kt < 5) STAGE(kt + 3, (kt + 3) & 3);       // distance-3 prefetch
                                                   // (overwrites buf (kt-1)&3,
                                                   //  reads sealed by barrier)

    // B fragment first (shared across both mt), then A per mt.
    // lane holds k = g*32 + [0,32) of its row as 2 x b128 (u_log = 2g,2g+1),
    // un-swizzled via u_phys = u_log ^ ((row>>2)&3)
    intx8 bf;
    {
      const int row = wn * 32 + m32;
      const int x = (row >> 2) & 3;
      int4 lo = *(const int4*)(&Bs[buf][row * 64 + ((2 * g)     ^ x) * 16]);
      int4 hi = *(const int4*)(&Bs[buf][row * 64 + ((2 * g + 1) ^ x) * 16]);
      intx8 f; f[0]=lo.x; f[1]=lo.y; f[2]=lo.z; f[3]=lo.w;
               f[4]=hi.x; f[5]=hi.y; f[6]=hi.z; f[7]=hi.w;
      bf = f;
    }
#pragma unroll
    for (int mt = 0; mt < 2; mt++) {
      const int row = wm * 64 + mt * 32 + m32;
      const int x = (row >> 2) & 3;
      int4 lo = *(const int4*)(&As[buf][row * 64 + ((2 * g)     ^ x) * 16]);
      int4 hi = *(const int4*)(&As[buf][row * 64 + ((2 * g + 1) ^ x) * 16]);
      intx8 af; af[0]=lo.x; af[1]=lo.y; af[2]=lo.z; af[3]=lo.w;
                af[4]=hi.x; af[5]=hi.y; af[6]=hi.z; af[7]=hi.w;
      acc[mt] = __builtin_amdgcn_mfma_scale_f32_32x32x64_f8f6f4(
          af, bf, acc[mt],
          0 /*A fmt: fp8 e4m3*/, 0 /*B fmt: fp8 e4m3*/,
          0, 127 /*scaleA = 2^0*/, 0, 127 /*scaleB = 2^0*/);
    }
  }

  // Epilogue (R0-verified). 32x32 C/D layout [m74/m101]: col = lane&31,
  // row = (reg&3) + 8*(reg>>2) + 4*(lane>>5), reg in [0,16).
  float lsum = 0.f;
  const bool diag = (bi == bj);
  const int  tc   = tg[colBase + wn * 32 + m32];
  if (!diag) {
#pragma unroll
    for (int mt = 0; mt < 2; mt++) {
#pragma unroll
      for (int q = 0; q < 4; q++) {
        const int4 rlv = *(const int4*)(tg + rowBase + wm * 64 + mt * 32 + 4 * g + 8 * q);
        const int rlab[4] = {rlv.x, rlv.y, rlv.z, rlv.w};
#pragma unroll
        for (int j = 0; j < 4; j++) {
          const float s = acc[mt][q * 4 + j];
          lsum += (rlab[j] == tc) ? ((s < 1.f) ? 1.f - s : 0.f)
                                  : ((s > MARGIN) ? s : 0.f);
        }
      }
    }
    lsum *= 2.f;     // pair weight hoisted
  } else {
    const int col = colBase + wn * 32 + m32;
#pragma unroll
    for (int mt = 0; mt < 2; mt++) {
#pragma unroll
      for (int q = 0; q < 4; q++) {
        const int rbase = wm * 64 + mt * 32 + 4 * g + 8 * q;
        const int4 rlv = *(const int4*)(tg + rowBase + rbase);
        const int rlab[4] = {rlv.x, rlv.y, rlv.z, rlv.w};
#pragma unroll
        for (int j = 0; j < 4; j++) {
          const float s = acc[mt][q * 4 + j];
          float c = (rlab[j] == tc) ? ((s < 1.f) ? 1.f - s : 0.f)
                                    : ((s > MARGIN) ? s : 0.f);
          const int row = rowBase + rbase + j;
          float wgt = (row < col) ? 2.f : ((row == col) ? 1.f : 0.f);
          lsum += wgt * c;
        }
      }
    }
  }

  // block reduce, ONE non-atomic partial store per block
#pragma unroll
  for (int off = 32; off > 0; off >>= 1) lsum += __shfl_down(lsum, off, 64);
  if (lane == 0) red[w] = lsum;
  __syncthreads();
  if (tid == 0) {
    float s = 0.f;
#pragma unroll
    for (int i = 0; i < 8; i++) s += red[i];
    partials[blockIdx.x] = s;
  }
#undef STAGE
}

// NT partials -> scalar; one 256-thread block
__global__ void reduce_kernel(const float* __restrict__ partials, float* __restrict__ out) {
  __shared__ float red[4];
  float s = 0.f;
  for (int i = threadIdx.x; i < NT; i += 256) s += partials[i];
#pragma unroll
  for (int off = 32; off > 0; off >>= 1) s += __shfl_down(s, off, 64);
  if ((threadIdx.x & 63) == 0) red[threadIdx.x >> 6] = s;
  __syncthreads();
  if (threadIdx.x == 0)
    out[0] = (red[0] + red[1] + red[2] + red[3]) * (1.0f / NROWS);
}

extern "C" void kernel_launch(void* const* d_in, const int* in_sizes, int n_in,
                              void* d_out, int out_size, void* d_ws, size_t ws_size,
                              hipStream_t stream) {
  const float* x = (const float*)d_in[0];
  const int* tg  = (const int*)d_in[1];
  float* out     = (float*)d_out;
  unsigned char* xb = (unsigned char*)d_ws;                    // fp8 X, 4 MiB
  float* partials   = (float*)((char*)d_ws + (4u << 20));      // NT floats

  convert_kernel<<<(NROWS * NDIM / 4) / 256, 256, 0, stream>>>(
      (const float4*)x, (unsigned*)xb);
  loss_kernel<<<NT, 512, 0, stream>>>(xb, tg, partials);
  reduce_kernel<<<1, 256, 0, stream>>>(partials, out);
}

// Round 15
// 96.140 us; speedup vs baseline: 1.0347x; 1.0347x over previous
//
#include <hip/hip_runtime.h>
#include <hip/hip_bf16.h>
#include <stdint.h>

#define NROWS 8192
#define NDIM  512
#define MARGIN 0.3f
#define NT    2080     // 64*65/2 upper-triangular 128x128 blocks

typedef __attribute__((ext_vector_type(16))) float floatx16;
typedef __attribute__((ext_vector_type(8)))  int   intx8;

// pack 4 floats -> 4 OCP e4m3 bytes (HW cvt, RNE, saturating)
__device__ inline unsigned cvt4_fp8(float4 f) {
  int v = 0;
  v = __builtin_amdgcn_cvt_pk_fp8_f32(f.x, f.y, v, false);
  v = __builtin_amdgcn_cvt_pk_fp8_f32(f.z, f.w, v, true);
  return (unsigned)v;
}

// fp32 -> fp8 e4m3, fully coalesced: lane i reads float4 i, writes u32 i
__global__ void convert_kernel(const float4* __restrict__ in, unsigned* __restrict__ out) {
  int i = blockIdx.x * blockDim.x + threadIdx.x;
  out[i] = cvt4_fp8(in[i]);
}

__device__ inline void gload_lds16(const void* g, void* l) {
  __builtin_amdgcn_global_load_lds(
      (const __attribute__((address_space(1))) unsigned int*)g,
      (__attribute__((address_space(3))) unsigned int*)l, 16, 0, 0);
}

// R30 = FINAL: byte-identical restore of the R7/R12 champion (94.7/95.2us).
// Session design-space bracket (14 structural probes):
//   tile {64^2,128^2,256^2} x waves/group {1,8,16} x stages {2,3,4} x
//   distance {1,2,3} x staging {DMA,direct} x reduce {separate,fused}
// Champion: 128^2 tile, 8 waves x 64x32, 3-stage BK=64 LDS, distance-2
// prefetch, per-step vmcnt(2) -> raw s_barrier -> stage-after-barrier,
// 16 waves/CU. All neighbors regress: dist-3 +4us (R14, DMA pressure),
// fused-reduce tail +35us (R11, regalloc perturbation), 16-wave groups
// +34us (R8, convoy), direct-global +94us (R9), 2-stage/1-blk 256^2 +10us
// (R3/R5), 1-wave +17us (R6). Timed-window decomposition: ~45us harness
// re-poison fill (uncontrollable) + ~3.5us convert + ~38us loss (latency-
// bound local optimum) + ~2us reduce/gaps ~= 95us.
__launch_bounds__(512, 4)
__global__ void loss_kernel(const unsigned char* __restrict__ Xb, const int* __restrict__ tg,
                            float* __restrict__ partials) {
  __shared__ __align__(16) unsigned char As[3][8192];   // 128 rows x 64 B
  __shared__ __align__(16) unsigned char Bs[3][8192];
  __shared__ float red[8];

  // super-tile decode (8 diagonal supers of 36, then 28 off-diag of 64)
  int t = blockIdx.x;
  int bi, bj;
  if (t < 288) {
    int si = t / 36;
    int q  = t - si * 36;
    int ii = 0;
    while (q >= 8 - ii) { q -= 8 - ii; ii++; }
    bi = si * 8 + ii;
    bj = si * 8 + ii + q;
  } else {
    int q = t - 288;
    int s = q >> 6, r = q & 63;
    int si = 0;
    while (s >= 7 - si) { s -= 7 - si; si++; }
    int sj = si + 1 + s;
    bi = si * 8 + (r >> 3);
    bj = sj * 8 + (r & 7);
  }

  const int tid  = threadIdx.x;
  const int lane = tid & 63;
  const int w    = tid >> 6;             // 0..7
  const int wm   = w >> 2, wn = w & 3;   // 2x4 waves, 64x32 each
  const int g    = lane >> 5;            // MFMA k-group (0/1)
  const int m32  = lane & 31;            // MFMA row/col within 32

  const int rowBase = bi * 128;
  const int colBase = bj * 128;

  // staging: tile = 128 rows x 64 B = 8 chunks of 1 KB (16 rows each);
  // wave w stages chunk w of A and chunk w of B (2 DMA loads/wave/stage).
  // Chunk lane d: row = w*16 + (d>>2), u_phys = d&3; fetches global k-unit
  // u_log = u_phys ^ ((row>>2)&3)  (conflict-free b128 reads, R14-verified;
  // (row>>2)&3 == (srow>>2)&3 since w*16 contributes 0 mod 4).
  const int srow = lane >> 2;
  const int sup  = lane & 3;
  const int ul   = sup ^ ((srow >> 2) & 3);
  const int rloc = w * 16 + srow;
  const unsigned gA = (unsigned)((rowBase + rloc) * NDIM + ul * 16);
  const unsigned gB = (unsigned)((colBase + rloc) * NDIM + ul * 16);

#define STAGE(KT, BUF)                                                    \
  do {                                                                    \
    gload_lds16(Xb + gA + (KT) * 64, &As[BUF][w * 1024]);                 \
    gload_lds16(Xb + gB + (KT) * 64, &Bs[BUF][w * 1024]);                 \
  } while (0)

  floatx16 acc[2];
  acc[0] = (floatx16)(0.f);
  acc[1] = (floatx16)(0.f);

  STAGE(0, 0);
  STAGE(1, 1);

#pragma unroll
  for (int kt = 0; kt < 8; kt++) {
    const int buf = kt % 3;
    // own stage kt landed (2 oldest loads retired); kt+1's 2 stay in flight.
    if (kt < 7) asm volatile("s_waitcnt vmcnt(2)" ::: "memory");
    else        asm volatile("s_waitcnt vmcnt(0)" ::: "memory");
    asm volatile("s_barrier" ::: "memory");        // raw: no lgkm drain
    if (kt < 6) STAGE(kt + 2, (kt + 2) % 3);       // distance-2 prefetch

    // B fragment first (shared across both mt), then A per mt.
    // lane holds k = g*32 + [0,32) of its row as 2 x b128 (u_log = 2g,2g+1),
    // un-swizzled via u_phys = u_log ^ ((row>>2)&3)
    intx8 bf;
    {
      const int row = wn * 32 + m32;
      const int x = (row >> 2) & 3;
      int4 lo = *(const int4*)(&Bs[buf][row * 64 + ((2 * g)     ^ x) * 16]);
      int4 hi = *(const int4*)(&Bs[buf][row * 64 + ((2 * g + 1) ^ x) * 16]);
      intx8 f; f[0]=lo.x; f[1]=lo.y; f[2]=lo.z; f[3]=lo.w;
               f[4]=hi.x; f[5]=hi.y; f[6]=hi.z; f[7]=hi.w;
      bf = f;
    }
#pragma unroll
    for (int mt = 0; mt < 2; mt++) {
      const int row = wm * 64 + mt * 32 + m32;
      const int x = (row >> 2) & 3;
      int4 lo = *(const int4*)(&As[buf][row * 64 + ((2 * g)     ^ x) * 16]);
      int4 hi = *(const int4*)(&As[buf][row * 64 + ((2 * g + 1) ^ x) * 16]);
      intx8 af; af[0]=lo.x; af[1]=lo.y; af[2]=lo.z; af[3]=lo.w;
                af[4]=hi.x; af[5]=hi.y; af[6]=hi.z; af[7]=hi.w;
      acc[mt] = __builtin_amdgcn_mfma_scale_f32_32x32x64_f8f6f4(
          af, bf, acc[mt],
          0 /*A fmt: fp8 e4m3*/, 0 /*B fmt: fp8 e4m3*/,
          0, 127 /*scaleA = 2^0*/, 0, 127 /*scaleB = 2^0*/);
    }
  }

  // Epilogue (R0-verified). 32x32 C/D layout [m74/m101]: col = lane&31,
  // row = (reg&3) + 8*(reg>>2) + 4*(lane>>5), reg in [0,16).
  float lsum = 0.f;
  const bool diag = (bi == bj);
  const int  tc   = tg[colBase + wn * 32 + m32];
  if (!diag) {
#pragma unroll
    for (int mt = 0; mt < 2; mt++) {
#pragma unroll
      for (int q = 0; q < 4; q++) {
        const int4 rlv = *(const int4*)(tg + rowBase + wm * 64 + mt * 32 + 4 * g + 8 * q);
        const int rlab[4] = {rlv.x, rlv.y, rlv.z, rlv.w};
#pragma unroll
        for (int j = 0; j < 4; j++) {
          const float s = acc[mt][q * 4 + j];
          lsum += (rlab[j] == tc) ? ((s < 1.f) ? 1.f - s : 0.f)
                                  : ((s > MARGIN) ? s : 0.f);
        }
      }
    }
    lsum *= 2.f;     // pair weight hoisted
  } else {
    const int col = colBase + wn * 32 + m32;
#pragma unroll
    for (int mt = 0; mt < 2; mt++) {
#pragma unroll
      for (int q = 0; q < 4; q++) {
        const int rbase = wm * 64 + mt * 32 + 4 * g + 8 * q;
        const int4 rlv = *(const int4*)(tg + rowBase + rbase);
        const int rlab[4] = {rlv.x, rlv.y, rlv.z, rlv.w};
#pragma unroll
        for (int j = 0; j < 4; j++) {
          const float s = acc[mt][q * 4 + j];
          float c = (rlab[j] == tc) ? ((s < 1.f) ? 1.f - s : 0.f)
                                    : ((s > MARGIN) ? s : 0.f);
          const int row = rowBase + rbase + j;
          float wgt = (row < col) ? 2.f : ((row == col) ? 1.f : 0.f);
          lsum += wgt * c;
        }
      }
    }
  }

  // block reduce, ONE non-atomic partial store per block
#pragma unroll
  for (int off = 32; off > 0; off >>= 1) lsum += __shfl_down(lsum, off, 64);
  if (lane == 0) red[w] = lsum;
  __syncthreads();
  if (tid == 0) {
    float s = 0.f;
#pragma unroll
    for (int i = 0; i < 8; i++) s += red[i];
    partials[blockIdx.x] = s;
  }
#undef STAGE
}

// NT partials -> scalar; one 256-thread block
__global__ void reduce_kernel(const float* __restrict__ partials, float* __restrict__ out) {
  __shared__ float red[4];
  float s = 0.f;
  for (int i = threadIdx.x; i < NT; i += 256) s += partials[i];
#pragma unroll
  for (int off = 32; off > 0; off >>= 1) s += __shfl_down(s, off, 64);
  if ((threadIdx.x & 63) == 0) red[threadIdx.x >> 6] = s;
  __syncthreads();
  if (threadIdx.x == 0)
    out[0] = (red[0] + red[1] + red[2] + red[3]) * (1.0f / NROWS);
}

extern "C" void kernel_launch(void* const* d_in, const int* in_sizes, int n_in,
                              void* d_out, int out_size, void* d_ws, size_t ws_size,
                              hipStream_t stream) {
  const float* x = (const float*)d_in[0];
  const int* tg  = (const int*)d_in[1];
  float* out     = (float*)d_out;
  unsigned char* xb = (unsigned char*)d_ws;                    // fp8 X, 4 MiB
  float* partials   = (float*)((char*)d_ws + (4u << 20));      // NT floats

  convert_kernel<<<(NROWS * NDIM / 4) / 256, 256, 0, stream>>>(
      (const float4*)x, (unsigned*)xb);
  loss_kernel<<<NT, 512, 0, stream>>>(xb, tg, partials);
  reduce_kernel<<<1, 256, 0, stream>>>(partials, out);
}